// Round 11
// baseline (170.486 us; speedup 1.0000x reference)
//
#include <hip/hip_runtime.h>
#include <hip/hip_bf16.h>
#include <math.h>

#define B_GRAPHS 512
#define MAXLEN   128
#define DDRUG    256
#define NH       16
#define EMB      1024

typedef __attribute__((ext_vector_type(4))) float f32x4;
typedef __attribute__((ext_vector_type(8))) short s16x8;
typedef __attribute__((ext_vector_type(4))) short s16x4;

__device__ inline short f2bf(float f) {               // RNE float->bf16
    unsigned u = __builtin_bit_cast(unsigned, f);
    u += 0x7FFF + ((u >> 16) & 1);
    return (short)(u >> 16);
}
__device__ inline float bf2f(short s) {
    unsigned u = ((unsigned)(unsigned short)s) << 16;
    return __builtin_bit_cast(float, u);
}

// async global->LDS direct copy, 16B per lane; LDS dest = wave-uniform base
// + lane*16 (HW rule), so the source address carries the swizzle (rule #21).
__device__ inline void gload16(const short* g, void* lds)
{
    __builtin_amdgcn_global_load_lds(
        (const __attribute__((address_space(1))) unsigned*)g,
        (__attribute__((address_space(3))) unsigned*)lds, 16, 0, 0);
}

__device__ inline void cvt4(const float* __restrict__ in, short* __restrict__ out, int j)
{
    f32x4 v = ((const f32x4*)in)[j];
    s16x4 o;
    o.x = f2bf(v.x); o.y = f2bf(v.y); o.z = f2bf(v.z); o.w = f2bf(v.w);
    ((s16x4*)out)[j] = o;
}

// ---------------------------------------------------------------------------
// prep: fused starts (lower_bound) + all fp32->bf16 converts + concat.
// ---------------------------------------------------------------------------
__global__ __launch_bounds__(256) void prep_kernel(
    const float* __restrict__ cell, const float* __restrict__ Wc,
    const float* __restrict__ Wq,   const float* __restrict__ Wo,
    const float* __restrict__ Wv,   const int* __restrict__ g32, int N,
    float* __restrict__ out, short* __restrict__ cell_bf, short* __restrict__ Wc_bf,
    short* __restrict__ Wq_bf, short* __restrict__ Wo_bf, short* __restrict__ Wv_bf,
    int* __restrict__ starts)
{
    const int stride = gridDim.x * 256;
    for (int i = blockIdx.x * 256 + threadIdx.x; i < 1114625; i += stride) {
        if      (i <  131072) cvt4(cell, cell_bf, i);
        else if (i <  393216) cvt4(Wc, Wc_bf, i - 131072);
        else if (i <  655360) cvt4(Wq, Wq_bf, i - 393216);
        else if (i <  917504) cvt4(Wo, Wo_bf, i - 655360);
        else if (i <  983040) cvt4(Wv, Wv_bf, i - 917504);
        else if (i < 1114112) {
            int j = i - 983040;                       // vec4 idx into cell
            int b = j >> 8, c4 = j & 255;
            *(f32x4*)&out[(size_t)b * 2048 + 1024 + c4 * 4] = ((const f32x4*)cell)[j];
        } else {
            int b = i - 1114112;                      // 0..512
            bool is64 = (g32[N - 1] == 0);            // odd index: int64 high word
            int lo = 0, hi = N;
            while (lo < hi) {
                int mid = (lo + hi) >> 1;
                int v = is64 ? g32[2 * mid] : g32[mid];
                if (v < b) lo = mid + 1; else hi = mid;
            }
            starts[b] = lo;
        }
    }
}

// ---------------------------------------------------------------------------
// C[M,N] = (A[M,K] * B[N,K]^T + bias[N]) * scale, A/B bf16.
// 32x32 tile, BK=64, 256 threads = 4 waves each one 16x16 MFMA frag.
// Staging via global_load_lds width-16 (m97 ladder step): linear LDS dest,
// inverse-swizzled global source; swizzled ds_read_b128 MFMA reads unchanged.
// ---------------------------------------------------------------------------
template<bool OUT_BF>
__global__ __launch_bounds__(256) void gemm32_bf16_nt(
    const short* __restrict__ A, int lda,
    const short* __restrict__ Bw, int ldb,
    const float* __restrict__ bias, void* __restrict__ Cout,
    int ldc, float scale, int K)
{
    __shared__ short As[32 * 64];
    __shared__ short Bs[32 * 64];
    const int t = threadIdx.x, lane = t & 63, w = t >> 6;
    const int wm = w >> 1, wn = w & 1;
    const int row0 = blockIdx.y * 32, col0 = blockIdx.x * 32;
    f32x4 c = {0.f, 0.f, 0.f, 0.f};

    // lane l of wave w fills LDS 16B-block blk = w*64+l = (row r, col-block c').
    // LDS block (r,c') must hold global col-block c'^(r&7)  (read-side XOR swz).
    const int blk = w * 64 + lane;
    const int r = blk >> 3, cp = blk & 7;
    const int gc = (cp ^ (r & 7)) * 8;                // element col within 64
    const short* gA = &A [(size_t)(row0 + r) * lda + gc];
    const short* gB = &Bw[(size_t)(col0 + r) * ldb + gc];
    char* ldsA = (char*)As + w * 1024;                // 64 lanes x 16B per wave
    char* ldsB = (char*)Bs + w * 1024;

    for (int kt = 0; kt < K; kt += 64) {
        gload16(gA + kt, ldsA);
        gload16(gB + kt, ldsB);
        __syncthreads();                              // drains vmcnt + lgkmcnt
        #pragma unroll
        for (int ks = 0; ks < 2; ++ks) {
            const int kk = (ks * 32 + (lane >> 4) * 8) * 2;   // byte col offset
            int ra = wm * 16 + (lane & 15);
            s16x8 a = *(const s16x8*)((char*)As + ra * 128 + (kk ^ ((ra & 7) << 4)));
            int rb = wn * 16 + (lane & 15);
            s16x8 b = *(const s16x8*)((char*)Bs + rb * 128 + (kk ^ ((rb & 7) << 4)));
            c = __builtin_amdgcn_mfma_f32_16x16x32_bf16(a, b, c, 0, 0, 0);
        }
        __syncthreads();
    }
    const int m0 = row0 + wm * 16 + (lane >> 4) * 4;
    const int nn = col0 + wn * 16 + (lane & 15);
    #pragma unroll
    for (int r2 = 0; r2 < 4; ++r2) {
        float v = (c[r2] + bias[nn]) * scale;
        if (OUT_BF) ((short*)Cout)[(size_t)(m0 + r2) * ldc + nn] = f2bf(v);
        else        ((float*)Cout)[(size_t)(m0 + r2) * ldc + nn] = v;
    }
}

// ---------------------------------------------------------------------------
// qk[b, h, d] = sum_j q[b, h*64+j] * Wk[h*64+j, d]   (fp32 in, bf16 out)
// ---------------------------------------------------------------------------
__global__ __launch_bounds__(256) void qk_kernel(
    const float* __restrict__ q, const float* __restrict__ Wk, short* __restrict__ qkout)
{
    __shared__ float q_s[8][64];
    const int bt = blockIdx.x, h = blockIdx.y, t = threadIdx.x;
    for (int i = t; i < 512; i += 256)
        q_s[i >> 6][i & 63] = q[(size_t)(bt * 8 + (i >> 6)) * EMB + h * 64 + (i & 63)];
    __syncthreads();
    float acc[8] = {};
    const float* wbase = &Wk[(size_t)h * 64 * DDRUG + t];
    #pragma unroll 4
    for (int j = 0; j < 64; ++j) {
        float wv = wbase[(size_t)j * DDRUG];
        #pragma unroll
        for (int bb = 0; bb < 8; ++bb) acc[bb] += q_s[bb][j] * wv;
    }
    #pragma unroll
    for (int bb = 0; bb < 8; ++bb)
        qkout[(size_t)(bt * 8 + bb) * 4096 + h * DDRUG + t] = f2bf(acc[bb]);
}

// ---------------------------------------------------------------------------
// Per-graph attention, one block per graph; X staged once into 64 KB swizzled
// LDS; scores via MFMA; two-pass softmax; xbar reads X from LDS.
// (Round 10: removed dup staging; attn left top-5.)
// ---------------------------------------------------------------------------
__global__ __launch_bounds__(256) void attn_kernel(
    const float* __restrict__ X, const short* __restrict__ qk,
    const int* __restrict__ starts, short* __restrict__ xbar, int Ntot)
{
    __shared__ short Xs[128 * 256];      // 64 KB swizzled bf16
    __shared__ float S_s[128 * 20];      // 10 KB scores/attn, pitch 20 (16B-aligned)
    const int b = blockIdx.x, t = threadIdx.x;
    const int lane = t & 63, w = t >> 6;
    const int s0 = starts[b];
    int n = starts[b + 1] - s0;
    if (n > MAXLEN) n = MAXLEN;

    // A-fragments straight from global (qk_bf just written -> L2-hot):
    s16x8 af[8];
    {
        const short* qb = qk + (size_t)b * 4096 + (lane & 15) * 256 + (lane >> 4) * 8;
        #pragma unroll
        for (int ks = 0; ks < 8; ++ks) af[ks] = *(const s16x8*)(qb + ks * 32);
    }

    const int sr = t >> 2, scg = (t & 3) * 64;        // X staging: row, col group
    auto stageX = [&](int st) {
        int lrow = st * 64 + sr;
        int gm = s0 + lrow;
        if (gm > Ntot - 1) gm = Ntot - 1;             // clamp (rows >= n are masked)
        const f32x4* src = (const f32x4*)(X + (size_t)gm * 256 + scg);
        int swzr = (sr & 7) << 4;                     // == (lrow&7)<<4 since 64%8==0
        #pragma unroll
        for (int j = 0; j < 8; ++j) {
            f32x4 a = src[2 * j], bb = src[2 * j + 1];
            s16x8 v;
            v[0] = f2bf(a.x);  v[1] = f2bf(a.y);  v[2] = f2bf(a.z);  v[3] = f2bf(a.w);
            v[4] = f2bf(bb.x); v[5] = f2bf(bb.y); v[6] = f2bf(bb.z); v[7] = f2bf(bb.w);
            *(s16x8*)((char*)Xs + lrow * 512 + (((scg + j * 8) * 2) ^ swzr)) = v;
        }
    };
    auto mfmaStage = [&](int st) {
        int lr = st * 64 + w * 16 + (lane & 15);
        int swzr = (lr & 7) << 4;
        f32x4 c = {0.f, 0.f, 0.f, 0.f};
        #pragma unroll
        for (int ks = 0; ks < 8; ++ks) {
            int k = ks * 32 + (lane >> 4) * 8;
            s16x8 bf = *(const s16x8*)((char*)Xs + lr * 512 + ((k * 2) ^ swzr));
            c = __builtin_amdgcn_mfma_f32_16x16x32_bf16(af[ks], bf, c, 0, 0, 0);
        }
        int hb = (lane >> 4) * 4;
        #pragma unroll
        for (int i = 0; i < 4; ++i) S_s[lr * 20 + hb + i] = c[i];
    };

    stageX(0);
    __syncthreads();
    if (n > 64) stageX(1);        // stage-1 HBM latency hides under mfma0
    mfmaStage(0);
    if (n > 64) {                 // block-uniform branch
        __syncthreads();
        mfmaStage(1);
    }
    __syncthreads();

    // masked softmax; wave w handles heads 4w..4w+3
    #pragma unroll
    for (int hh = 0; hh < 4; ++hh) {
        int h = w * 4 + hh;
        float v0 = (lane < n)      ? S_s[lane * 20 + h]        : -INFINITY;
        float v1 = (lane + 64 < n) ? S_s[(lane + 64) * 20 + h] : -INFINITY;
        float mx = fmaxf(v0, v1);
        #pragma unroll
        for (int off = 32; off > 0; off >>= 1) mx = fmaxf(mx, __shfl_xor(mx, off, 64));
        float e0 = (lane < n)      ? __expf(v0 - mx) : 0.f;
        float e1 = (lane + 64 < n) ? __expf(v1 - mx) : 0.f;
        float sm = e0 + e1;
        #pragma unroll
        for (int off = 32; off > 0; off >>= 1) sm += __shfl_xor(sm, off, 64);
        float inv = 1.f / sm;
        if (lane < n)      S_s[lane * 20 + h]        = e0 * inv;
        if (lane + 64 < n) S_s[(lane + 64) * 20 + h] = e1 * inv;
    }
    __syncthreads();

    // xbar[h][d] = sum_m P[m][h] * X[m][d]; thread owns d = t.
    const int d = t;
    float acc[16] = {};
    #pragma unroll 2
    for (int m = 0; m < n; ++m) {
        float x = bf2f(*(const short*)((char*)Xs + m * 512 + ((2 * d) ^ ((m & 7) << 4))));
        const f32x4* prow = (const f32x4*)&S_s[m * 20];
        f32x4 p0 = prow[0], p1 = prow[1], p2 = prow[2], p3 = prow[3];
        acc[0]  += p0.x * x; acc[1]  += p0.y * x; acc[2]  += p0.z * x; acc[3]  += p0.w * x;
        acc[4]  += p1.x * x; acc[5]  += p1.y * x; acc[6]  += p1.z * x; acc[7]  += p1.w * x;
        acc[8]  += p2.x * x; acc[9]  += p2.y * x; acc[10] += p2.z * x; acc[11] += p2.w * x;
        acc[12] += p3.x * x; acc[13] += p3.y * x; acc[14] += p3.z * x; acc[15] += p3.w * x;
    }
    short* xb = xbar + (size_t)b * 4096 + d;
    #pragma unroll
    for (int h = 0; h < 16; ++h) xb[(size_t)h * 256] = f2bf(acc[h]);
}

// ---------------------------------------------------------------------------
// outh: per-head mini-GEMM (unchanged; ~9 us implied by round 6 delta).
// ---------------------------------------------------------------------------
__global__ __launch_bounds__(256) void outh_gemm(
    const short* __restrict__ xbar,   // [512][4096] bf16, head h at cols h*256..
    const short* __restrict__ Wv_bf,  // [1024][256] bf16
    const float* __restrict__ bv, short* __restrict__ outh)
{
    __shared__ short As[64 * 64];
    __shared__ short Bs[64 * 64];
    const int t = threadIdx.x, lane = t & 63, w = t >> 6;
    const int wm = w >> 1, wn = w & 1;
    const int h = blockIdx.y;
    const int row0 = blockIdx.x * 64;                 // b tile
    const short* A = xbar + (size_t)h * 256;          // row stride 4096
    const short* B = Wv_bf + (size_t)h * 64 * 256;    // row stride 256
    f32x4 c[2][2] = {};

    const int sr = t >> 2, sc = (t & 3) * 16;
    const int swz = (sr & 7) << 4;
    const int kb0 = (lane >> 4) * 8;

    for (int kt = 0; kt < 256; kt += 64) {
        s16x8 va0 = *(const s16x8*)&A[(size_t)(row0 + sr) * 4096 + kt + sc];
        s16x8 va1 = *(const s16x8*)&A[(size_t)(row0 + sr) * 4096 + kt + sc + 8];
        s16x8 vb0 = *(const s16x8*)&B[(size_t)sr * 256 + kt + sc];
        s16x8 vb1 = *(const s16x8*)&B[(size_t)sr * 256 + kt + sc + 8];
        *(s16x8*)((char*)As + sr * 128 + ((sc * 2)      ^ swz)) = va0;
        *(s16x8*)((char*)As + sr * 128 + ((sc * 2 + 16) ^ swz)) = va1;
        *(s16x8*)((char*)Bs + sr * 128 + ((sc * 2)      ^ swz)) = vb0;
        *(s16x8*)((char*)Bs + sr * 128 + ((sc * 2 + 16) ^ swz)) = vb1;
        __syncthreads();
        #pragma unroll
        for (int ks = 0; ks < 2; ++ks) {
            const int kk = (ks * 32 + kb0) * 2;
            s16x8 a0, a1, b0, b1;
            {
                int r = wm * 32 + (lane & 15);
                a0 = *(const s16x8*)((char*)As + r * 128 + (kk ^ ((r & 7) << 4)));
                int r2 = r + 16;
                a1 = *(const s16x8*)((char*)As + r2 * 128 + (kk ^ ((r2 & 7) << 4)));
            }
            {
                int r = wn * 32 + (lane & 15);
                b0 = *(const s16x8*)((char*)Bs + r * 128 + (kk ^ ((r & 7) << 4)));
                int r2 = r + 16;
                b1 = *(const s16x8*)((char*)Bs + r2 * 128 + (kk ^ ((r2 & 7) << 4)));
            }
            c[0][0] = __builtin_amdgcn_mfma_f32_16x16x32_bf16(a0, b0, c[0][0], 0, 0, 0);
            c[0][1] = __builtin_amdgcn_mfma_f32_16x16x32_bf16(a0, b1, c[0][1], 0, 0, 0);
            c[1][0] = __builtin_amdgcn_mfma_f32_16x16x32_bf16(a1, b0, c[1][0], 0, 0, 0);
            c[1][1] = __builtin_amdgcn_mfma_f32_16x16x32_bf16(a1, b1, c[1][1], 0, 0, 0);
        }
        __syncthreads();
    }
    #pragma unroll
    for (int i = 0; i < 2; ++i)
    #pragma unroll
    for (int j = 0; j < 2; ++j) {
        int m0 = row0 + wm * 32 + i * 16 + (lane >> 4) * 4;   // b index
        int nn = wn * 32 + j * 16 + (lane & 15);              // j within head
        #pragma unroll
        for (int r = 0; r < 4; ++r) {
            float v = c[i][j][r] + bv[h * 64 + nn];
            outh[(size_t)(m0 + r) * EMB + h * 64 + nn] = f2bf(v);
        }
    }
}

// ---------------------------------------------------------------------------
extern "C" void kernel_launch(void* const* d_in, const int* in_sizes, int n_in,
                              void* d_out, int out_size, void* d_ws, size_t ws_size,
                              hipStream_t stream)
{
    const float* x_nodes = (const float*)d_in[0];
    const float* cell    = (const float*)d_in[1];
    const float* Wq      = (const float*)d_in[2];
    const float* bq      = (const float*)d_in[3];
    const float* Wk      = (const float*)d_in[4];
    // d_in[5] = bk: softmax-invariant, dropped
    const float* Wv      = (const float*)d_in[6];
    const float* bv      = (const float*)d_in[7];
    const float* Wo      = (const float*)d_in[8];
    const float* bo      = (const float*)d_in[9];
    const float* Wc      = (const float*)d_in[10];
    const float* bc      = (const float*)d_in[11];
    const int*   guide   = (const int*)d_in[12];
    const int N = in_sizes[12];
    float* out = (float*)d_out;

    // workspace layout (~19.5 MB); all slots disjoint.
    char* ws = (char*)d_ws;
    int*   starts  = (int*)ws;
    float* qf32    = (float*)(ws + 4096);                    // 2 MB
    short* cell_bf = (short*)(ws + 4096 + (2u << 20));       // 1 MB
    short* cq_bf   = (short*)(ws + 4096 + (3u << 20));       // 1 MB
    short* outh_bf = (short*)(ws + 4096 + (4u << 20));       // 1 MB
    short* qk_bf   = (short*)(ws + 4096 + (5u << 20));       // 4 MB
    short* xbar_bf = (short*)(ws + 4096 + (9u << 20));       // 4 MB
    short* Wc_bf   = (short*)(ws + 4096 + (13u << 20));      // 2 MB
    short* Wq_bf   = (short*)(ws + 4096 + (15u << 20));      // 2 MB
    short* Wo_bf   = (short*)(ws + 4096 + (17u << 20));      // 2 MB
    short* Wv_bf   = (short*)(ws + 4096 + (19u << 20));      // 0.5 MB

    // 1) fused prep: starts + all converts + concat
    prep_kernel<<<2048, 256, 0, stream>>>(
        cell, Wc, Wq, Wo, Wv, guide, N, out,
        cell_bf, Wc_bf, Wq_bf, Wo_bf, Wv_bf, starts);

    // 2) cq = cell @ Wc^T + bc           (bf16 out)
    gemm32_bf16_nt<true ><<<dim3(32, 16), 256, 0, stream>>>(
        cell_bf, 1024, Wc_bf, 1024, bc, cq_bf, 1024, 1.0f, 1024);
    // 3) q = (cq @ Wq^T + bq) * 0.125    (fp32 out)
    gemm32_bf16_nt<false><<<dim3(32, 16), 256, 0, stream>>>(
        cq_bf, 1024, Wq_bf, 1024, bq, qf32, 1024, 0.125f, 1024);

    // 4) qk pre-contraction
    qk_kernel<<<dim3(B_GRAPHS / 8, NH), 256, 0, stream>>>(qf32, Wk, qk_bf);

    // 5) attention (one block per graph, X LDS-resident)
    attn_kernel<<<B_GRAPHS, 256, 0, stream>>>(x_nodes, qk_bf, starts, xbar_bf, N);

    // 6) outh = blockdiag(xbar . Wv^T) + bv
    outh_gemm<<<dim3(8, NH), 256, 0, stream>>>(xbar_bf, Wv_bf, bv, outh_bf);

    // 7) out[:, :1024] = outh @ Wo^T + bo  (fp32, ldc=2048 -> concat layout)
    gemm32_bf16_nt<false><<<dim3(32, 16), 256, 0, stream>>>(
        outh_bf, 1024, Wo_bf, 1024, bo, out, 2048, 1.0f, 1024);

    (void)in_sizes; (void)n_in; (void)out_size; (void)ws_size;
}

// Round 12
// 165.194 us; speedup vs baseline: 1.0320x; 1.0320x over previous
//
#include <hip/hip_runtime.h>
#include <hip/hip_bf16.h>
#include <math.h>

#define B_GRAPHS 512
#define MAXLEN   128
#define DDRUG    256
#define NH       16
#define EMB      1024

typedef __attribute__((ext_vector_type(4))) float f32x4;
typedef __attribute__((ext_vector_type(8))) short s16x8;
typedef __attribute__((ext_vector_type(4))) short s16x4;

__device__ inline short f2bf(float f) {               // RNE float->bf16
    unsigned u = __builtin_bit_cast(unsigned, f);
    u += 0x7FFF + ((u >> 16) & 1);
    return (short)(u >> 16);
}
__device__ inline float bf2f(short s) {
    unsigned u = ((unsigned)(unsigned short)s) << 16;
    return __builtin_bit_cast(float, u);
}

// async global->LDS direct copy, 16B per lane (kept from r11: neutral, valid)
__device__ inline void gload16(const short* g, void* lds)
{
    __builtin_amdgcn_global_load_lds(
        (const __attribute__((address_space(1))) unsigned*)g,
        (__attribute__((address_space(3))) unsigned*)lds, 16, 0, 0);
}

__device__ inline void cvt4(const float* __restrict__ in, short* __restrict__ out, int j)
{
    f32x4 v = ((const f32x4*)in)[j];
    s16x4 o;
    o.x = f2bf(v.x); o.y = f2bf(v.y); o.z = f2bf(v.z); o.w = f2bf(v.w);
    ((s16x4*)out)[j] = o;
}

// ---------------------------------------------------------------------------
// prep: fused starts (lower_bound) + all fp32->bf16 converts + concat.
// ---------------------------------------------------------------------------
__global__ __launch_bounds__(256) void prep_kernel(
    const float* __restrict__ cell, const float* __restrict__ Wc,
    const float* __restrict__ Wq,   const float* __restrict__ Wo,
    const float* __restrict__ Wv,   const int* __restrict__ g32, int N,
    float* __restrict__ out, short* __restrict__ cell_bf, short* __restrict__ Wc_bf,
    short* __restrict__ Wq_bf, short* __restrict__ Wo_bf, short* __restrict__ Wv_bf,
    int* __restrict__ starts)
{
    const int stride = gridDim.x * 256;
    for (int i = blockIdx.x * 256 + threadIdx.x; i < 1114625; i += stride) {
        if      (i <  131072) cvt4(cell, cell_bf, i);
        else if (i <  393216) cvt4(Wc, Wc_bf, i - 131072);
        else if (i <  655360) cvt4(Wq, Wq_bf, i - 393216);
        else if (i <  917504) cvt4(Wo, Wo_bf, i - 655360);
        else if (i <  983040) cvt4(Wv, Wv_bf, i - 917504);
        else if (i < 1114112) {
            int j = i - 983040;                       // vec4 idx into cell
            int b = j >> 8, c4 = j & 255;
            *(f32x4*)&out[(size_t)b * 2048 + 1024 + c4 * 4] = ((const f32x4*)cell)[j];
        } else {
            int b = i - 1114112;                      // 0..512
            bool is64 = (g32[N - 1] == 0);            // odd index: int64 high word
            int lo = 0, hi = N;
            while (lo < hi) {
                int mid = (lo + hi) >> 1;
                int v = is64 ? g32[2 * mid] : g32[mid];
                if (v < b) lo = mid + 1; else hi = mid;
            }
            starts[b] = lo;
        }
    }
}

// ---------------------------------------------------------------------------
// C[M,N] = (A[M,K] * B[N,K]^T + bias[N]) * scale, A/B bf16.  (unchanged r11)
// ---------------------------------------------------------------------------
template<bool OUT_BF>
__global__ __launch_bounds__(256) void gemm32_bf16_nt(
    const short* __restrict__ A, int lda,
    const short* __restrict__ Bw, int ldb,
    const float* __restrict__ bias, void* __restrict__ Cout,
    int ldc, float scale, int K)
{
    __shared__ short As[32 * 64];
    __shared__ short Bs[32 * 64];
    const int t = threadIdx.x, lane = t & 63, w = t >> 6;
    const int wm = w >> 1, wn = w & 1;
    const int row0 = blockIdx.y * 32, col0 = blockIdx.x * 32;
    f32x4 c = {0.f, 0.f, 0.f, 0.f};

    const int blk = w * 64 + lane;
    const int r = blk >> 3, cp = blk & 7;
    const int gc = (cp ^ (r & 7)) * 8;                // inverse-swz global col
    const short* gA = &A [(size_t)(row0 + r) * lda + gc];
    const short* gB = &Bw[(size_t)(col0 + r) * ldb + gc];
    char* ldsA = (char*)As + w * 1024;
    char* ldsB = (char*)Bs + w * 1024;

    for (int kt = 0; kt < K; kt += 64) {
        gload16(gA + kt, ldsA);
        gload16(gB + kt, ldsB);
        __syncthreads();
        #pragma unroll
        for (int ks = 0; ks < 2; ++ks) {
            const int kk = (ks * 32 + (lane >> 4) * 8) * 2;
            int ra = wm * 16 + (lane & 15);
            s16x8 a = *(const s16x8*)((char*)As + ra * 128 + (kk ^ ((ra & 7) << 4)));
            int rb = wn * 16 + (lane & 15);
            s16x8 b = *(const s16x8*)((char*)Bs + rb * 128 + (kk ^ ((rb & 7) << 4)));
            c = __builtin_amdgcn_mfma_f32_16x16x32_bf16(a, b, c, 0, 0, 0);
        }
        __syncthreads();
    }
    const int m0 = row0 + wm * 16 + (lane >> 4) * 4;
    const int nn = col0 + wn * 16 + (lane & 15);
    #pragma unroll
    for (int r2 = 0; r2 < 4; ++r2) {
        float v = (c[r2] + bias[nn]) * scale;
        if (OUT_BF) ((short*)Cout)[(size_t)(m0 + r2) * ldc + nn] = f2bf(v);
        else        ((float*)Cout)[(size_t)(m0 + r2) * ldc + nn] = v;
    }
}

// ---------------------------------------------------------------------------
// qk[b, h, d] = sum_j q[b, h*64+j] * Wk[h*64+j, d]   (fp32 in, bf16 out)
// ---------------------------------------------------------------------------
__global__ __launch_bounds__(256) void qk_kernel(
    const float* __restrict__ q, const float* __restrict__ Wk, short* __restrict__ qkout)
{
    __shared__ float q_s[8][64];
    const int bt = blockIdx.x, h = blockIdx.y, t = threadIdx.x;
    for (int i = t; i < 512; i += 256)
        q_s[i >> 6][i & 63] = q[(size_t)(bt * 8 + (i >> 6)) * EMB + h * 64 + (i & 63)];
    __syncthreads();
    float acc[8] = {};
    const float* wbase = &Wk[(size_t)h * 64 * DDRUG + t];
    #pragma unroll 4
    for (int j = 0; j < 64; ++j) {
        float wv = wbase[(size_t)j * DDRUG];
        #pragma unroll
        for (int bb = 0; bb < 8; ++bb) acc[bb] += q_s[bb][j] * wv;
    }
    #pragma unroll
    for (int bb = 0; bb < 8; ++bb)
        qkout[(size_t)(bt * 8 + bb) * 4096 + h * DDRUG + t] = f2bf(acc[bb]);
}

// ---------------------------------------------------------------------------
// Per-graph attention, 512 threads / 8 waves (was 256/4 at 25% occupancy):
// - stage ONLY rows < n (r10 staged all 128 incl. other graphs' rows: ~2x X
//   traffic), one pass, 8 waves
// - all 8 MFMA row-tiles in one pass; waves with w*16 >= n skip
// - softmax: 2 heads/wave
// - xbar m-loop split in half across thread groups (t>>8), LDS partial
//   combine overlaid on then-dead Xs (sync-fenced)
// LDS 74 KB -> 2 blocks/CU = 16 waves/CU (50%).
// ---------------------------------------------------------------------------
__global__ __launch_bounds__(512) void attn_kernel(
    const float* __restrict__ X, const short* __restrict__ qk,
    const int* __restrict__ starts, short* __restrict__ xbar, int Ntot)
{
    __shared__ short Xs[128 * 256];      // 64 KB swizzled bf16
    __shared__ float S_s[128 * 20];      // 10 KB scores/attn, pitch 20
    const int b = blockIdx.x, t = threadIdx.x;
    const int lane = t & 63, w = t >> 6;
    const int s0 = starts[b];
    int n = starts[b + 1] - s0;
    if (n > MAXLEN) n = MAXLEN;

    // A-fragments straight from global (qk_bf L2-hot):
    s16x8 af[8];
    {
        const short* qb = qk + (size_t)b * 4096 + (lane & 15) * 256 + (lane >> 4) * 8;
        #pragma unroll
        for (int ks = 0; ks < 8; ++ks) af[ks] = *(const s16x8*)(qb + ks * 32);
    }

    // stage: row = t>>2 (0..127), 4 threads/row, 64 elems each; only rows < n
    {
        const int row = t >> 2, scg = (t & 3) * 64;
        if (row < n) {
            const f32x4* src = (const f32x4*)(X + (size_t)(s0 + row) * 256 + scg);
            int swzr = (row & 7) << 4;
            #pragma unroll
            for (int j = 0; j < 8; ++j) {
                f32x4 a = src[2 * j], bb = src[2 * j + 1];
                s16x8 v;
                v[0] = f2bf(a.x);  v[1] = f2bf(a.y);  v[2] = f2bf(a.z);  v[3] = f2bf(a.w);
                v[4] = f2bf(bb.x); v[5] = f2bf(bb.y); v[6] = f2bf(bb.z); v[7] = f2bf(bb.w);
                *(s16x8*)((char*)Xs + row * 512 + (((scg + j * 8) * 2) ^ swzr)) = v;
            }
        }
    }
    __syncthreads();

    // S^T MFMA: wave w owns rows w*16..+16 (skip if fully masked).
    // D: col=lane&15 (=m within tile), row=(lane>>4)*4+i (=h).
    if (w * 16 < n) {
        int lr = w * 16 + (lane & 15);
        int swzr = (lr & 7) << 4;
        f32x4 c = {0.f, 0.f, 0.f, 0.f};
        #pragma unroll
        for (int ks = 0; ks < 8; ++ks) {
            int k = ks * 32 + (lane >> 4) * 8;
            s16x8 bf = *(const s16x8*)((char*)Xs + lr * 512 + ((k * 2) ^ swzr));
            c = __builtin_amdgcn_mfma_f32_16x16x32_bf16(af[ks], bf, c, 0, 0, 0);
        }
        int hb = (lane >> 4) * 4;
        #pragma unroll
        for (int i = 0; i < 4; ++i) S_s[lr * 20 + hb + i] = c[i];
    }
    __syncthreads();

    // masked softmax; wave w handles heads 2w, 2w+1
    #pragma unroll
    for (int hh = 0; hh < 2; ++hh) {
        int h = w * 2 + hh;
        float v0 = (lane < n)      ? S_s[lane * 20 + h]        : -INFINITY;
        float v1 = (lane + 64 < n) ? S_s[(lane + 64) * 20 + h] : -INFINITY;
        float mx = fmaxf(v0, v1);
        #pragma unroll
        for (int off = 32; off > 0; off >>= 1) mx = fmaxf(mx, __shfl_xor(mx, off, 64));
        float e0 = (lane < n)      ? __expf(v0 - mx) : 0.f;
        float e1 = (lane + 64 < n) ? __expf(v1 - mx) : 0.f;
        float sm = e0 + e1;
        #pragma unroll
        for (int off = 32; off > 0; off >>= 1) sm += __shfl_xor(sm, off, 64);
        float inv = 1.f / sm;
        if (lane < n)      S_s[lane * 20 + h]        = e0 * inv;
        if (lane + 64 < n) S_s[(lane + 64) * 20 + h] = e1 * inv;
    }
    __syncthreads();

    // xbar[h][d] = sum_m P[m][h]*X[m][d]; thread owns d = t&255, m-half = t>>8
    const int d = t & 255, half = t >> 8;
    float acc[16] = {};
    {
        int mlo = half * 64;
        int mhi = n < mlo + 64 ? n : mlo + 64;
        for (int m = mlo; m < mhi; ++m) {
            float x = bf2f(*(const short*)((char*)Xs + m * 512 + ((2 * d) ^ ((m & 7) << 4))));
            const f32x4* prow = (const f32x4*)&S_s[m * 20];
            f32x4 p0 = prow[0], p1 = prow[1], p2 = prow[2], p3 = prow[3];
            acc[0]  += p0.x * x; acc[1]  += p0.y * x; acc[2]  += p0.z * x; acc[3]  += p0.w * x;
            acc[4]  += p1.x * x; acc[5]  += p1.y * x; acc[6]  += p1.z * x; acc[7]  += p1.w * x;
            acc[8]  += p2.x * x; acc[9]  += p2.y * x; acc[10] += p2.z * x; acc[11] += p2.w * x;
            acc[12] += p3.x * x; acc[13] += p3.y * x; acc[14] += p3.z * x; acc[15] += p3.w * x;
        }
    }
    __syncthreads();                                  // Xs reads done everywhere
    float* pd = (float*)Xs;                           // 16 KB overlay on dead Xs
    if (half == 1) {
        #pragma unroll
        for (int h = 0; h < 16; ++h) pd[h * 256 + d] = acc[h];
    }
    __syncthreads();
    if (half == 0) {
        short* xb = xbar + (size_t)b * 4096 + d;
        #pragma unroll
        for (int h = 0; h < 16; ++h)
            xb[(size_t)h * 256] = f2bf(acc[h] + pd[h * 256 + d]);
    }
}

// ---------------------------------------------------------------------------
// outh: per-head mini-GEMM (unchanged).
// ---------------------------------------------------------------------------
__global__ __launch_bounds__(256) void outh_gemm(
    const short* __restrict__ xbar,   // [512][4096] bf16, head h at cols h*256..
    const short* __restrict__ Wv_bf,  // [1024][256] bf16
    const float* __restrict__ bv, short* __restrict__ outh)
{
    __shared__ short As[64 * 64];
    __shared__ short Bs[64 * 64];
    const int t = threadIdx.x, lane = t & 63, w = t >> 6;
    const int wm = w >> 1, wn = w & 1;
    const int h = blockIdx.y;
    const int row0 = blockIdx.x * 64;                 // b tile
    const short* A = xbar + (size_t)h * 256;          // row stride 4096
    const short* B = Wv_bf + (size_t)h * 64 * 256;    // row stride 256
    f32x4 c[2][2] = {};

    const int sr = t >> 2, sc = (t & 3) * 16;
    const int swz = (sr & 7) << 4;
    const int kb0 = (lane >> 4) * 8;

    for (int kt = 0; kt < 256; kt += 64) {
        s16x8 va0 = *(const s16x8*)&A[(size_t)(row0 + sr) * 4096 + kt + sc];
        s16x8 va1 = *(const s16x8*)&A[(size_t)(row0 + sr) * 4096 + kt + sc + 8];
        s16x8 vb0 = *(const s16x8*)&B[(size_t)sr * 256 + kt + sc];
        s16x8 vb1 = *(const s16x8*)&B[(size_t)sr * 256 + kt + sc + 8];
        *(s16x8*)((char*)As + sr * 128 + ((sc * 2)      ^ swz)) = va0;
        *(s16x8*)((char*)As + sr * 128 + ((sc * 2 + 16) ^ swz)) = va1;
        *(s16x8*)((char*)Bs + sr * 128 + ((sc * 2)      ^ swz)) = vb0;
        *(s16x8*)((char*)Bs + sr * 128 + ((sc * 2 + 16) ^ swz)) = vb1;
        __syncthreads();
        #pragma unroll
        for (int ks = 0; ks < 2; ++ks) {
            const int kk = (ks * 32 + kb0) * 2;
            s16x8 a0, a1, b0, b1;
            {
                int r = wm * 32 + (lane & 15);
                a0 = *(const s16x8*)((char*)As + r * 128 + (kk ^ ((r & 7) << 4)));
                int r2 = r + 16;
                a1 = *(const s16x8*)((char*)As + r2 * 128 + (kk ^ ((r2 & 7) << 4)));
            }
            {
                int r = wn * 32 + (lane & 15);
                b0 = *(const s16x8*)((char*)Bs + r * 128 + (kk ^ ((r & 7) << 4)));
                int r2 = r + 16;
                b1 = *(const s16x8*)((char*)Bs + r2 * 128 + (kk ^ ((r2 & 7) << 4)));
            }
            c[0][0] = __builtin_amdgcn_mfma_f32_16x16x32_bf16(a0, b0, c[0][0], 0, 0, 0);
            c[0][1] = __builtin_amdgcn_mfma_f32_16x16x32_bf16(a0, b1, c[0][1], 0, 0, 0);
            c[1][0] = __builtin_amdgcn_mfma_f32_16x16x32_bf16(a1, b0, c[1][0], 0, 0, 0);
            c[1][1] = __builtin_amdgcn_mfma_f32_16x16x32_bf16(a1, b1, c[1][1], 0, 0, 0);
        }
        __syncthreads();
    }
    #pragma unroll
    for (int i = 0; i < 2; ++i)
    #pragma unroll
    for (int j = 0; j < 2; ++j) {
        int m0 = row0 + wm * 32 + i * 16 + (lane >> 4) * 4;   // b index
        int nn = wn * 32 + j * 16 + (lane & 15);              // j within head
        #pragma unroll
        for (int r = 0; r < 4; ++r) {
            float v = c[i][j][r] + bv[h * 64 + nn];
            outh[(size_t)(m0 + r) * EMB + h * 64 + nn] = f2bf(v);
        }
    }
}

// ---------------------------------------------------------------------------
extern "C" void kernel_launch(void* const* d_in, const int* in_sizes, int n_in,
                              void* d_out, int out_size, void* d_ws, size_t ws_size,
                              hipStream_t stream)
{
    const float* x_nodes = (const float*)d_in[0];
    const float* cell    = (const float*)d_in[1];
    const float* Wq      = (const float*)d_in[2];
    const float* bq      = (const float*)d_in[3];
    const float* Wk      = (const float*)d_in[4];
    // d_in[5] = bk: softmax-invariant, dropped
    const float* Wv      = (const float*)d_in[6];
    const float* bv      = (const float*)d_in[7];
    const float* Wo      = (const float*)d_in[8];
    const float* bo      = (const float*)d_in[9];
    const float* Wc      = (const float*)d_in[10];
    const float* bc      = (const float*)d_in[11];
    const int*   guide   = (const int*)d_in[12];
    const int N = in_sizes[12];
    float* out = (float*)d_out;

    // workspace layout (~19.5 MB); all slots disjoint.
    char* ws = (char*)d_ws;
    int*   starts  = (int*)ws;
    float* qf32    = (float*)(ws + 4096);                    // 2 MB
    short* cell_bf = (short*)(ws + 4096 + (2u << 20));       // 1 MB
    short* cq_bf   = (short*)(ws + 4096 + (3u << 20));       // 1 MB
    short* outh_bf = (short*)(ws + 4096 + (4u << 20));       // 1 MB
    short* qk_bf   = (short*)(ws + 4096 + (5u << 20));       // 4 MB
    short* xbar_bf = (short*)(ws + 4096 + (9u << 20));       // 4 MB
    short* Wc_bf   = (short*)(ws + 4096 + (13u << 20));      // 2 MB
    short* Wq_bf   = (short*)(ws + 4096 + (15u << 20));      // 2 MB
    short* Wo_bf   = (short*)(ws + 4096 + (17u << 20));      // 2 MB
    short* Wv_bf   = (short*)(ws + 4096 + (19u << 20));      // 0.5 MB

    // 1) fused prep: starts + all converts + concat
    prep_kernel<<<2048, 256, 0, stream>>>(
        cell, Wc, Wq, Wo, Wv, guide, N, out,
        cell_bf, Wc_bf, Wq_bf, Wo_bf, Wv_bf, starts);

    // 2) cq = cell @ Wc^T + bc           (bf16 out)
    gemm32_bf16_nt<true ><<<dim3(32, 16), 256, 0, stream>>>(
        cell_bf, 1024, Wc_bf, 1024, bc, cq_bf, 1024, 1.0f, 1024);
    // 3) q = (cq @ Wq^T + bq) * 0.125    (fp32 out)
    gemm32_bf16_nt<false><<<dim3(32, 16), 256, 0, stream>>>(
        cq_bf, 1024, Wq_bf, 1024, bq, qf32, 1024, 0.125f, 1024);

    // 4) qk pre-contraction
    qk_kernel<<<dim3(B_GRAPHS / 8, NH), 256, 0, stream>>>(qf32, Wk, qk_bf);

    // 5) attention (one 512-thread block per graph, X LDS-resident)
    attn_kernel<<<B_GRAPHS, 512, 0, stream>>>(x_nodes, qk_bf, starts, xbar_bf, N);

    // 6) outh = blockdiag(xbar . Wv^T) + bv
    outh_gemm<<<dim3(8, NH), 256, 0, stream>>>(xbar_bf, Wv_bf, bv, outh_bf);

    // 7) out[:, :1024] = outh @ Wo^T + bo  (fp32, ldc=2048 -> concat layout)
    gemm32_bf16_nt<false><<<dim3(32, 16), 256, 0, stream>>>(
        outh_bf, 1024, Wo_bf, 1024, bo, out, 2048, 1.0f, 1024);

    (void)in_sizes; (void)n_in; (void)out_size; (void)ws_size;
}